// Round 2
// baseline (1001.671 us; speedup 1.0000x reference)
//
#include <hip/hip_runtime.h>

// ---------------------------------------------------------------------------
// GQA attention block: QKV proj -> RoPE -> causal GQA flash attention -> out proj
// B=2 S=2048 D=4096 NH=32 NKV=8 HD=128 (QKV_DIM=6144)
// All heavy math in bf16 MFMA (16x16x32), fp32 accumulate/softmax.
// R2: gemm_bt restructured to m97 pattern — global_load_lds width=16 staging,
//     unpadded LDS (stride 32), 2-barrier K-loop.
// ---------------------------------------------------------------------------

typedef __bf16 bf16;
typedef bf16 bf16x8 __attribute__((ext_vector_type(8)));
typedef bf16 bf16x4 __attribute__((ext_vector_type(4)));
typedef float f32x4 __attribute__((ext_vector_type(4)));

#define B_ 2
#define S_ 2048
#define DM 4096
#define NH 32
#define NKV 8
#define HD 128
#define QKV_DIM 6144

typedef __attribute__((address_space(3))) void lds_void;
typedef const __attribute__((address_space(1))) void glb_void;

__device__ __forceinline__ void gld_lds16(const bf16* g, bf16* l) {
  __builtin_amdgcn_global_load_lds((glb_void*)g, (lds_void*)l, 16, 0, 0);
}

// ---------------- cast fp32 -> bf16 (hidden states) ----------------
__global__ __launch_bounds__(256) void cast_f32_bf16(const float* __restrict__ src,
                                                     bf16* __restrict__ dst, int n) {
  int i = (blockIdx.x * 256 + threadIdx.x) * 4;
  float4 v = *(const float4*)(src + i);
  bf16x4 o;
  o[0] = (bf16)v.x; o[1] = (bf16)v.y; o[2] = (bf16)v.z; o[3] = (bf16)v.w;
  *(bf16x4*)(dst + i) = o;
}

// ---------------- transpose + cast weights: W[K][N] f32 -> Wt[N][K] bf16 ----
__global__ __launch_bounds__(256) void transpose_cast_w(const float* __restrict__ W,
                                                        bf16* __restrict__ Wt,
                                                        int K, int N) {
  __shared__ float tile[64][65];
  const int n0 = blockIdx.x * 64, k0 = blockIdx.y * 64;
  const int t = threadIdx.x, j = t & 63, i0 = t >> 6;
  for (int p = 0; p < 16; ++p) {
    int i = i0 + p * 4;
    tile[i][j] = W[(size_t)(k0 + i) * N + n0 + j];
  }
  __syncthreads();
  for (int p = 0; p < 16; ++p) {
    int n = i0 + p * 4;
    Wt[(size_t)(n0 + n) * K + k0 + j] = (bf16)tile[j][n];
  }
}

// ---------------- transpose V out of qkv: v_t[b][kv][d][s] ----------------
__global__ __launch_bounds__(256) void transpose_v(const bf16* __restrict__ qkv,
                                                   bf16* __restrict__ v_t) {
  __shared__ bf16 tile[64][65];
  const int s0 = blockIdx.x * 64;
  const int d0 = blockIdx.y * 64;
  const int bk = blockIdx.z;            // b*8+kv
  const int b = bk >> 3, kv = bk & 7;
  const int t = threadIdx.x, j = t & 63, i0 = t >> 6;
  const bf16* src = qkv + (size_t)b * S_ * QKV_DIM + 5120 + kv * HD;  // v offset 5120
  for (int p = 0; p < 16; ++p) {
    int i = i0 + p * 4;
    tile[i][j] = src[(size_t)(s0 + i) * QKV_DIM + d0 + j];
  }
  __syncthreads();
  bf16* dst = v_t + ((size_t)bk * HD + d0) * S_ + s0;
  for (int p = 0; p < 16; ++p) {
    int dd = i0 + p * 4;
    dst[(size_t)dd * S_ + j] = tile[j][dd];
  }
}

// ---------------- RoPE + repack q,k (q pre-scaled by 1/sqrt(HD)) ----------
__global__ __launch_bounds__(128) void rope_kernel(const bf16* __restrict__ qkv,
                                                   const float* __restrict__ cosT,
                                                   const float* __restrict__ sinT,
                                                   bf16* __restrict__ q_r,
                                                   bf16* __restrict__ k_r) {
  const int bs = blockIdx.x;            // b*S + s
  const int b = bs >> 11, s = bs & 2047;
  const int d = threadIdx.x;            // 0..127
  const float cv = cosT[s * HD + d];
  const float sv = sinT[s * HD + d];
  const bf16* row = qkv + (size_t)bs * QKV_DIM;
  const float scale = 0.08838834764831845f;  // 1/sqrt(128)
  for (int h = 0; h < NH; ++h) {
    float x = (float)row[h * HD + d];
    float xr = (d < 64) ? -(float)row[h * HD + d + 64] : (float)row[h * HD + d - 64];
    q_r[(((size_t)(b * NH + h)) * S_ + s) * HD + d] = (bf16)((x * cv + xr * sv) * scale);
  }
  for (int kv = 0; kv < NKV; ++kv) {
    float x = (float)row[DM + kv * HD + d];
    float xr = (d < 64) ? -(float)row[DM + kv * HD + d + 64] : (float)row[DM + kv * HD + d - 64];
    k_r[(((size_t)(b * NKV + kv)) * S_ + s) * HD + d] = (bf16)(x * cv + xr * sv);
  }
}

// ---------------- GEMM: C[M][N] = A[M][K] * Bt[N][K]^T (bf16, f32 acc) -----
// m97 structure: 128x128 tile, BK=32, 4 waves (2x2), each wave 64x64 = 4x4
// mfma_16x16x32 tiles. Staging via global_load_lds dwordx4 (DMA to LDS,
// unpadded stride-32 layout), 2 barriers per K-iter.
template <bool OUT_BF16>
__global__ __launch_bounds__(256) void gemm_bt(const bf16* __restrict__ A,
                                               const bf16* __restrict__ Bt,
                                               void* __restrict__ Cout,
                                               int M, int N, int K) {
  __shared__ bf16 As[128 * 32];   // unpadded: global_load_lds needs lane-contiguous
  __shared__ bf16 Bs[128 * 32];
  const int m0 = blockIdx.y * 128, n0 = blockIdx.x * 128;
  const int t = threadIdx.x;
  const int lane = t & 63, w = t >> 6;
  const int wm = (w >> 1) * 64, wn = (w & 1) * 64;
  const int quad = lane >> 4, c = lane & 15;

  f32x4 acc[4][4] = {};

  // staging geometry: segment s in [0,512) covers LDS elements [s*8, s*8+8)
  // = tile row s>>2, cols (s&3)*8. Instr i in {0,1}: s = i*256 + w*64 + lane.
  const int s0i = t;              // i=0 segment for this thread
  const int r0 = s0i >> 2, c0 = (s0i & 3) * 8;
  const int s1i = 256 + t;        // i=1 segment
  const int r1 = s1i >> 2, c1 = (s1i & 3) * 8;
  const bf16* Ap0 = A + (size_t)(m0 + r0) * K + c0;
  const bf16* Ap1 = A + (size_t)(m0 + r1) * K + c1;
  const bf16* Bp0 = Bt + (size_t)(n0 + r0) * K + c0;
  const bf16* Bp1 = Bt + (size_t)(n0 + r1) * K + c1;
  // wave-uniform LDS bases (HW adds lane*16 bytes)
  bf16* Asl0 = As + (size_t)(w * 64) * 8;
  bf16* Asl1 = As + (size_t)(256 + w * 64) * 8;
  bf16* Bsl0 = Bs + (size_t)(w * 64) * 8;
  bf16* Bsl1 = Bs + (size_t)(256 + w * 64) * 8;

  for (int k0 = 0; k0 < K; k0 += 32) {
    gld_lds16(Ap0 + k0, Asl0);
    gld_lds16(Ap1 + k0, Asl1);
    gld_lds16(Bp0 + k0, Bsl0);
    gld_lds16(Bp1 + k0, Bsl1);
    __syncthreads();   // drains vmcnt(0): staging visible to all waves

    bf16x8 af[4], bfr[4];
#pragma unroll
    for (int i = 0; i < 4; ++i)
      af[i] = *(const bf16x8*)(As + (wm + i * 16 + c) * 32 + quad * 8);
#pragma unroll
    for (int j = 0; j < 4; ++j)
      bfr[j] = *(const bf16x8*)(Bs + (wn + j * 16 + c) * 32 + quad * 8);
#pragma unroll
    for (int i = 0; i < 4; ++i)
#pragma unroll
      for (int j = 0; j < 4; ++j)
        acc[i][j] = __builtin_amdgcn_mfma_f32_16x16x32_bf16(af[i], bfr[j], acc[i][j], 0, 0, 0);
    __syncthreads();   // all frag reads done before next iter's DMA overwrites
  }

#pragma unroll
  for (int i = 0; i < 4; ++i)
#pragma unroll
    for (int j = 0; j < 4; ++j) {
      const int row = m0 + wm + i * 16 + quad * 4;
      const int col = n0 + wn + j * 16 + c;
      if constexpr (OUT_BF16) {
        bf16* Cp = (bf16*)Cout;
#pragma unroll
        for (int r = 0; r < 4; ++r) Cp[(size_t)(row + r) * N + col] = (bf16)acc[i][j][r];
      } else {
        float* Cp = (float*)Cout;
#pragma unroll
        for (int r = 0; r < 4; ++r) Cp[(size_t)(row + r) * N + col] = acc[i][j][r];
      }
    }
}

// ---------------- flash attention (causal GQA) -----------------------------
// grid: (B*NH, S/64). 4 waves/block, wave w owns q rows [q0+16w, q0+16w+16).
// K-chunk = 32 keys. Ks[key][d] (+8 pad), Vs[d][key] (+8 pad), per-wave Ps.
#define SKS 136
#define SVS 40
#define SPS 40
__global__ __launch_bounds__(256) void attn_kernel(const bf16* __restrict__ q_r,
                                                   const bf16* __restrict__ k_r,
                                                   const bf16* __restrict__ v_t,
                                                   bf16* __restrict__ attn_out) {
  __shared__ bf16 Ks[32 * SKS];
  __shared__ bf16 Vs[128 * SVS];
  __shared__ bf16 Ps[4 * 16 * SPS];

  const int bh = blockIdx.x;           // b*NH + h
  const int b = bh >> 5, h = bh & 31;
  const int kv = h >> 2;               // N_GROUPS = 4
  const int q0 = blockIdx.y * 64;
  const int t = threadIdx.x, w = t >> 6, lane = t & 63;
  const int quad = lane >> 4, c = lane & 15;

  // Q fragments (held in registers across the whole K loop)
  const bf16* qrow = q_r + ((size_t)(b * NH + h) * S_ + (q0 + w * 16 + c)) * HD;
  bf16x8 qf[4];
#pragma unroll
  for (int kk = 0; kk < 4; ++kk) qf[kk] = *(const bf16x8*)(qrow + quad * 8 + kk * 32);

  float m_i[4], l_i[4];
  f32x4 o_acc[8];
#pragma unroll
  for (int r = 0; r < 4; ++r) { m_i[r] = -1e30f; l_i[r] = 0.f; }
#pragma unroll
  for (int n = 0; n < 8; ++n) o_acc[n] = (f32x4){0.f, 0.f, 0.f, 0.f};

  const bf16* kb_ptr = k_r + (size_t)(b * NKV + kv) * S_ * HD;
  const bf16* vb_ptr = v_t + (size_t)(b * NKV + kv) * HD * S_;
  bf16* Psw = Ps + w * 16 * SPS;

  const int nch = (q0 + 64) >> 5;
  const int ks_key = t >> 3, ks_doff = (t & 7) * 16;
  const int vs_d = t >> 1, vs_koff = (t & 1) * 16;

  for (int ch = 0; ch < nch; ++ch) {
    const int kb = ch * 32;
    __syncthreads();   // previous chunk's LDS reads done before overwrite
    {
      const bf16* kp = kb_ptr + (size_t)(kb + ks_key) * HD + ks_doff;
      bf16x8 kv0 = *(const bf16x8*)(kp);
      bf16x8 kv1 = *(const bf16x8*)(kp + 8);
      const bf16* vp = vb_ptr + (size_t)vs_d * S_ + kb + vs_koff;
      bf16x8 vv0 = *(const bf16x8*)(vp);
      bf16x8 vv1 = *(const bf16x8*)(vp + 8);
      *(bf16x8*)(Ks + ks_key * SKS + ks_doff) = kv0;
      *(bf16x8*)(Ks + ks_key * SKS + ks_doff + 8) = kv1;
      *(bf16x8*)(Vs + vs_d * SVS + vs_koff) = vv0;
      *(bf16x8*)(Vs + vs_d * SVS + vs_koff + 8) = vv1;
    }
    __syncthreads();

    // S = Q K^T  (scale pre-applied to Q)
    f32x4 s0 = (f32x4){0.f, 0.f, 0.f, 0.f};
    f32x4 s1 = (f32x4){0.f, 0.f, 0.f, 0.f};
#pragma unroll
    for (int kk = 0; kk < 4; ++kk) {
      bf16x8 kf0 = *(const bf16x8*)(Ks + c * SKS + quad * 8 + kk * 32);
      bf16x8 kf1 = *(const bf16x8*)(Ks + (16 + c) * SKS + quad * 8 + kk * 32);
      s0 = __builtin_amdgcn_mfma_f32_16x16x32_bf16(qf[kk], kf0, s0, 0, 0, 0);
      s1 = __builtin_amdgcn_mfma_f32_16x16x32_bf16(qf[kk], kf1, s1, 0, 0, 0);
    }

    // online softmax (rows quad*4+r; 16-lane quad-group reductions)
    float alpha[4];
#pragma unroll
    for (int r = 0; r < 4; ++r) {
      const int row = q0 + w * 16 + quad * 4 + r;
      float v0 = s0[r], v1 = s1[r];
      if (kb + c > row) v0 = -1e30f;
      if (kb + 16 + c > row) v1 = -1e30f;
      float mx = fmaxf(v0, v1);
#pragma unroll
      for (int off = 1; off < 16; off <<= 1) mx = fmaxf(mx, __shfl_xor(mx, off, 64));
      const float mnew = fmaxf(m_i[r], mx);
      const float p0 = __expf(v0 - mnew);
      const float p1 = __expf(v1 - mnew);
      float sum = p0 + p1;
#pragma unroll
      for (int off = 1; off < 16; off <<= 1) sum += __shfl_xor(sum, off, 64);
      alpha[r] = __expf(m_i[r] - mnew);
      m_i[r] = mnew;
      l_i[r] = l_i[r] * alpha[r] + sum;
      Psw[(quad * 4 + r) * SPS + c] = (bf16)p0;
      Psw[(quad * 4 + r) * SPS + 16 + c] = (bf16)p1;
    }

    // rescale O
#pragma unroll
    for (int n = 0; n < 8; ++n)
#pragma unroll
      for (int r = 0; r < 4; ++r) o_acc[n][r] *= alpha[r];

    __syncthreads();   // order Ps cross-lane writes before A-frag reads

    // O += P V
    bf16x8 pf = *(const bf16x8*)(Psw + c * SPS + quad * 8);
#pragma unroll
    for (int n = 0; n < 8; ++n) {
      bf16x8 vf = *(const bf16x8*)(Vs + (n * 16 + c) * SVS + quad * 8);
      o_acc[n] = __builtin_amdgcn_mfma_f32_16x16x32_bf16(pf, vf, o_acc[n], 0, 0, 0);
    }
  }

  // epilogue: O /= l, write attn_out[b][s][h*128+d]
#pragma unroll
  for (int n = 0; n < 8; ++n)
#pragma unroll
    for (int r = 0; r < 4; ++r) {
      const int row = q0 + w * 16 + quad * 4 + r;
      const float ov = o_acc[n][r] / l_i[r];
      attn_out[((size_t)b * S_ + row) * DM + h * HD + n * 16 + c] = (bf16)ov;
    }
}

// ---------------------------------------------------------------------------
extern "C" void kernel_launch(void* const* d_in, const int* in_sizes, int n_in,
                              void* d_out, int out_size, void* d_ws, size_t ws_size,
                              hipStream_t stream) {
  const float* hidden = (const float*)d_in[0];
  const float* cosT = (const float*)d_in[1];
  const float* sinT = (const float*)d_in[2];
  const float* Wqkv = (const float*)d_in[3];
  const float* Wout = (const float*)d_in[4];
  float* out = (float*)d_out;
  char* ws = (char*)d_ws;

  // workspace layout (regions reused once dead):
  //   [0, 50.3MB):   WqkvT (k2..k3)  -> q_r [0,33.5MB) + k_r [33.5,41.9MB) (k4+)
  //   [50.3, 83.9):  WoutT (k2..k7)
  //   [83.9, 117.4): h_bf16 (k1,k3)  -> attn_out (k6..k7)
  //   [117.4,125.8): v_t (k5..k6)
  // qkv (50.3MB bf16) lives in d_out (67.1MB), dead before final GEMM writes.
  bf16* WqkvT = (bf16*)(ws + 0);
  bf16* q_r = (bf16*)(ws + 0);
  bf16* k_r = (bf16*)(ws + 33554432);
  bf16* WoutT = (bf16*)(ws + 50331648);
  bf16* h_bf = (bf16*)(ws + 83886080);
  bf16* attn_out = (bf16*)(ws + 83886080);
  bf16* v_t = (bf16*)(ws + 117440512);
  bf16* qkv = (bf16*)d_out;

  // 1. cast hidden -> bf16
  cast_f32_bf16<<<dim3(16384), dim3(256), 0, stream>>>(hidden, h_bf, B_ * S_ * DM);
  // 2. transpose+cast weights
  transpose_cast_w<<<dim3(QKV_DIM / 64, DM / 64), dim3(256), 0, stream>>>(Wqkv, WqkvT, DM, QKV_DIM);
  transpose_cast_w<<<dim3(DM / 64, DM / 64), dim3(256), 0, stream>>>(Wout, WoutT, DM, DM);
  // 3. QKV projection (writes bf16 qkv into d_out region)
  gemm_bt<true><<<dim3(QKV_DIM / 128, (B_ * S_) / 128), dim3(256), 0, stream>>>(
      h_bf, WqkvT, (void*)qkv, B_ * S_, QKV_DIM, DM);
  // 4. RoPE + repack q,k
  rope_kernel<<<dim3(B_ * S_), dim3(128), 0, stream>>>(qkv, cosT, sinT, q_r, k_r);
  // 5. transpose V
  transpose_v<<<dim3(S_ / 64, HD / 64, B_ * NKV), dim3(256), 0, stream>>>(qkv, v_t);
  // 6. flash attention
  attn_kernel<<<dim3(B_ * NH, S_ / 64), dim3(256), 0, stream>>>(q_r, k_r, v_t, attn_out);
  // 7. output projection (fp32 out)
  gemm_bt<false><<<dim3(DM / 128, (B_ * S_) / 128), dim3(256), 0, stream>>>(
      attn_out, WoutT, (void*)out, B_ * S_, DM, DM);
}

// Round 3
// 933.423 us; speedup vs baseline: 1.0731x; 1.0731x over previous
//
#include <hip/hip_runtime.h>

// ---------------------------------------------------------------------------
// GQA attention block: QKV proj -> RoPE -> causal GQA flash attention -> out proj
// B=2 S=2048 D=4096 NH=32 NKV=8 HD=128 (QKV_DIM=6144)
// All heavy math in bf16 MFMA (16x16x32), fp32 accumulate/softmax.
// R2: gemm_bt uses global_load_lds width=16 staging, unpadded LDS, 2-barrier loop.
// R3: attention rewritten transposed-S: S^T = K*Q^T so each lane owns one q-row
//     -> softmax reductions in-register (2 shfl vs 32), P->A-layout via 8
//     bpermutes (no LDS round-trip), 2 barriers/chunk instead of 3.
// ---------------------------------------------------------------------------

typedef __bf16 bf16;
typedef bf16 bf16x8 __attribute__((ext_vector_type(8)));
typedef bf16 bf16x4 __attribute__((ext_vector_type(4)));
typedef float f32x4 __attribute__((ext_vector_type(4)));
typedef unsigned int u32;
typedef u32 u32x4 __attribute__((ext_vector_type(4)));

#define B_ 2
#define S_ 2048
#define DM 4096
#define NH 32
#define NKV 8
#define HD 128
#define QKV_DIM 6144

typedef __attribute__((address_space(3))) void lds_void;
typedef const __attribute__((address_space(1))) void glb_void;

__device__ __forceinline__ void gld_lds16(const bf16* g, bf16* l) {
  __builtin_amdgcn_global_load_lds((glb_void*)g, (lds_void*)l, 16, 0, 0);
}

__device__ __forceinline__ u32 bf16bits(float x) {
  union { bf16 h; unsigned short s; } u;
  u.h = (bf16)x;
  return (u32)u.s;
}

// ---------------- cast fp32 -> bf16 (hidden states) ----------------
__global__ __launch_bounds__(256) void cast_f32_bf16(const float* __restrict__ src,
                                                     bf16* __restrict__ dst, int n) {
  int i = (blockIdx.x * 256 + threadIdx.x) * 4;
  float4 v = *(const float4*)(src + i);
  bf16x4 o;
  o[0] = (bf16)v.x; o[1] = (bf16)v.y; o[2] = (bf16)v.z; o[3] = (bf16)v.w;
  *(bf16x4*)(dst + i) = o;
}

// ---------------- transpose + cast weights: W[K][N] f32 -> Wt[N][K] bf16 ----
__global__ __launch_bounds__(256) void transpose_cast_w(const float* __restrict__ W,
                                                        bf16* __restrict__ Wt,
                                                        int K, int N) {
  __shared__ float tile[64][65];
  const int n0 = blockIdx.x * 64, k0 = blockIdx.y * 64;
  const int t = threadIdx.x, j = t & 63, i0 = t >> 6;
  for (int p = 0; p < 16; ++p) {
    int i = i0 + p * 4;
    tile[i][j] = W[(size_t)(k0 + i) * N + n0 + j];
  }
  __syncthreads();
  for (int p = 0; p < 16; ++p) {
    int n = i0 + p * 4;
    Wt[(size_t)(n0 + n) * K + k0 + j] = (bf16)tile[j][n];
  }
}

// ---------------- transpose V out of qkv: v_t[b][kv][d][s] ----------------
__global__ __launch_bounds__(256) void transpose_v(const bf16* __restrict__ qkv,
                                                   bf16* __restrict__ v_t) {
  __shared__ bf16 tile[64][65];
  const int s0 = blockIdx.x * 64;
  const int d0 = blockIdx.y * 64;
  const int bk = blockIdx.z;            // b*8+kv
  const int b = bk >> 3, kv = bk & 7;
  const int t = threadIdx.x, j = t & 63, i0 = t >> 6;
  const bf16* src = qkv + (size_t)b * S_ * QKV_DIM + 5120 + kv * HD;  // v offset 5120
  for (int p = 0; p < 16; ++p) {
    int i = i0 + p * 4;
    tile[i][j] = src[(size_t)(s0 + i) * QKV_DIM + d0 + j];
  }
  __syncthreads();
  bf16* dst = v_t + ((size_t)bk * HD + d0) * S_ + s0;
  for (int p = 0; p < 16; ++p) {
    int dd = i0 + p * 4;
    dst[(size_t)dd * S_ + j] = tile[j][dd];
  }
}

// ---------------- RoPE + repack q,k (q pre-scaled by 1/sqrt(HD)) ----------
__global__ __launch_bounds__(128) void rope_kernel(const bf16* __restrict__ qkv,
                                                   const float* __restrict__ cosT,
                                                   const float* __restrict__ sinT,
                                                   bf16* __restrict__ q_r,
                                                   bf16* __restrict__ k_r) {
  const int bs = blockIdx.x;            // b*S + s
  const int b = bs >> 11, s = bs & 2047;
  const int d = threadIdx.x;            // 0..127
  const float cv = cosT[s * HD + d];
  const float sv = sinT[s * HD + d];
  const bf16* row = qkv + (size_t)bs * QKV_DIM;
  const float scale = 0.08838834764831845f;  // 1/sqrt(128)
  for (int h = 0; h < NH; ++h) {
    float x = (float)row[h * HD + d];
    float xr = (d < 64) ? -(float)row[h * HD + d + 64] : (float)row[h * HD + d - 64];
    q_r[(((size_t)(b * NH + h)) * S_ + s) * HD + d] = (bf16)((x * cv + xr * sv) * scale);
  }
  for (int kv = 0; kv < NKV; ++kv) {
    float x = (float)row[DM + kv * HD + d];
    float xr = (d < 64) ? -(float)row[DM + kv * HD + d + 64] : (float)row[DM + kv * HD + d - 64];
    k_r[(((size_t)(b * NKV + kv)) * S_ + s) * HD + d] = (bf16)(x * cv + xr * sv);
  }
}

// ---------------- GEMM: C[M][N] = A[M][K] * Bt[N][K]^T (bf16, f32 acc) -----
// m97 structure: 128x128 tile, BK=32, 4 waves (2x2), each wave 64x64 = 4x4
// mfma_16x16x32 tiles. Staging via global_load_lds dwordx4.
template <bool OUT_BF16>
__global__ __launch_bounds__(256) void gemm_bt(const bf16* __restrict__ A,
                                               const bf16* __restrict__ Bt,
                                               void* __restrict__ Cout,
                                               int M, int N, int K) {
  __shared__ bf16 As[128 * 32];   // unpadded: global_load_lds needs lane-contiguous
  __shared__ bf16 Bs[128 * 32];
  const int m0 = blockIdx.y * 128, n0 = blockIdx.x * 128;
  const int t = threadIdx.x;
  const int lane = t & 63, w = t >> 6;
  const int wm = (w >> 1) * 64, wn = (w & 1) * 64;
  const int quad = lane >> 4, c = lane & 15;

  f32x4 acc[4][4] = {};

  const int s0i = t;
  const int r0 = s0i >> 2, c0 = (s0i & 3) * 8;
  const int s1i = 256 + t;
  const int r1 = s1i >> 2, c1 = (s1i & 3) * 8;
  const bf16* Ap0 = A + (size_t)(m0 + r0) * K + c0;
  const bf16* Ap1 = A + (size_t)(m0 + r1) * K + c1;
  const bf16* Bp0 = Bt + (size_t)(n0 + r0) * K + c0;
  const bf16* Bp1 = Bt + (size_t)(n0 + r1) * K + c1;
  bf16* Asl0 = As + (size_t)(w * 64) * 8;
  bf16* Asl1 = As + (size_t)(256 + w * 64) * 8;
  bf16* Bsl0 = Bs + (size_t)(w * 64) * 8;
  bf16* Bsl1 = Bs + (size_t)(256 + w * 64) * 8;

  for (int k0 = 0; k0 < K; k0 += 32) {
    gld_lds16(Ap0 + k0, Asl0);
    gld_lds16(Ap1 + k0, Asl1);
    gld_lds16(Bp0 + k0, Bsl0);
    gld_lds16(Bp1 + k0, Bsl1);
    __syncthreads();

    bf16x8 af[4], bfr[4];
#pragma unroll
    for (int i = 0; i < 4; ++i)
      af[i] = *(const bf16x8*)(As + (wm + i * 16 + c) * 32 + quad * 8);
#pragma unroll
    for (int j = 0; j < 4; ++j)
      bfr[j] = *(const bf16x8*)(Bs + (wn + j * 16 + c) * 32 + quad * 8);
#pragma unroll
    for (int i = 0; i < 4; ++i)
#pragma unroll
      for (int j = 0; j < 4; ++j)
        acc[i][j] = __builtin_amdgcn_mfma_f32_16x16x32_bf16(af[i], bfr[j], acc[i][j], 0, 0, 0);
    __syncthreads();
  }

#pragma unroll
  for (int i = 0; i < 4; ++i)
#pragma unroll
    for (int j = 0; j < 4; ++j) {
      const int row = m0 + wm + i * 16 + quad * 4;
      const int col = n0 + wn + j * 16 + c;
      if constexpr (OUT_BF16) {
        bf16* Cp = (bf16*)Cout;
#pragma unroll
        for (int r = 0; r < 4; ++r) Cp[(size_t)(row + r) * N + col] = (bf16)acc[i][j][r];
      } else {
        float* Cp = (float*)Cout;
#pragma unroll
        for (int r = 0; r < 4; ++r) Cp[(size_t)(row + r) * N + col] = acc[i][j][r];
      }
    }
}

// ---------------- flash attention (causal GQA, transposed-S) ---------------
// grid: (B*NH, S/64). 4 waves/block, wave w owns q rows [q0+16w, q0+16w+16).
// K-chunk = 32 keys. Ks[key][d] (+8 pad), Vs[d][key] (+8 pad).
// S^T = K*Q^T: lane (c,quad) holds 8 scores (2 key-tiles x 4 regs) for the
// single q-row q0+16w+c -> softmax reduces in-register + 2 shfl. P converted
// to MFMA A-layout via 8 bpermutes (packed bf16 pairs), no LDS round-trip.
#define SKS 136
#define SVS 40
__global__ __launch_bounds__(256) void attn_kernel(const bf16* __restrict__ q_r,
                                                   const bf16* __restrict__ k_r,
                                                   const bf16* __restrict__ v_t,
                                                   bf16* __restrict__ attn_out) {
  __shared__ bf16 Ks[32 * SKS];
  __shared__ bf16 Vs[128 * SVS];

  const int bh = blockIdx.x;           // b*NH + h
  const int b = bh >> 5, h = bh & 31;
  const int kv = h >> 2;               // N_GROUPS = 4
  const int q0 = blockIdx.y * 64;
  const int t = threadIdx.x, w = t >> 6, lane = t & 63;
  const int quad = lane >> 4, c = lane & 15;
  const int myq = q0 + w * 16 + c;     // the q row this lane owns for softmax

  // Q B-frags (B[n=q][k=d]), held in registers across the whole K loop
  const bf16* qrow = q_r + ((size_t)(b * NH + h) * S_ + myq) * HD;
  bf16x8 qf[4];
#pragma unroll
  for (int kk = 0; kk < 4; ++kk) qf[kk] = *(const bf16x8*)(qrow + quad * 8 + kk * 32);

  float m_i = -1e30f, l_i = 0.f;       // per-lane (row = myq)
  f32x4 o_acc[8];
#pragma unroll
  for (int n = 0; n < 8; ++n) o_acc[n] = (f32x4){0.f, 0.f, 0.f, 0.f};

  const bf16* kb_ptr = k_r + (size_t)(b * NKV + kv) * S_ * HD;
  const bf16* vb_ptr = v_t + (size_t)(b * NKV + kv) * HD * S_;

  const int nch = (q0 + 64) >> 5;
  const int ks_key = t >> 3, ks_doff = (t & 7) * 16;
  const int vs_d = t >> 1, vs_koff = (t & 1) * 16;
  // P-conversion shuffle sources: lane (c,quad) pulls key 8q+j from
  // lane c+32*(quad&1) (j<4) / +16 (j>=4); key-tile select = quad>>1.
  const int src0 = c + 32 * (quad & 1);
  const int src1 = src0 + 16;
  const bool hiTile = (quad & 2) != 0;

  for (int ch = 0; ch < nch; ++ch) {
    const int kb = ch * 32;
    __syncthreads();   // previous chunk's LDS reads done before overwrite
    {
      const bf16* kp = kb_ptr + (size_t)(kb + ks_key) * HD + ks_doff;
      bf16x8 kv0 = *(const bf16x8*)(kp);
      bf16x8 kv1 = *(const bf16x8*)(kp + 8);
      const bf16* vp = vb_ptr + (size_t)vs_d * S_ + kb + vs_koff;
      bf16x8 vv0 = *(const bf16x8*)(vp);
      bf16x8 vv1 = *(const bf16x8*)(vp + 8);
      *(bf16x8*)(Ks + ks_key * SKS + ks_doff) = kv0;
      *(bf16x8*)(Ks + ks_key * SKS + ks_doff + 8) = kv1;
      *(bf16x8*)(Vs + vs_d * SVS + vs_koff) = vv0;
      *(bf16x8*)(Vs + vs_d * SVS + vs_koff + 8) = vv1;
    }
    __syncthreads();

    if (kb <= q0 + w * 16 + 15) {      // wave has at least one unmasked key
      // S^T = K Q^T : two 16(key)x16(q) tiles; A-frag = K rows, B-frag = Q
      f32x4 st0 = (f32x4){0.f, 0.f, 0.f, 0.f};
      f32x4 st1 = (f32x4){0.f, 0.f, 0.f, 0.f};
#pragma unroll
      for (int kk = 0; kk < 4; ++kk) {
        bf16x8 kf0 = *(const bf16x8*)(Ks + c * SKS + quad * 8 + kk * 32);
        bf16x8 kf1 = *(const bf16x8*)(Ks + (16 + c) * SKS + quad * 8 + kk * 32);
        st0 = __builtin_amdgcn_mfma_f32_16x16x32_bf16(kf0, qf[kk], st0, 0, 0, 0);
        st1 = __builtin_amdgcn_mfma_f32_16x16x32_bf16(kf1, qf[kk], st1, 0, 0, 0);
      }

      // masking (keys kb+16*kt+quad*4+r vs row myq)
      float v0[4], v1[4];
      const bool needMask = (kb + 31 > q0 + w * 16);
#pragma unroll
      for (int r = 0; r < 4; ++r) { v0[r] = st0[r]; v1[r] = st1[r]; }
      if (needMask) {
        const int key0 = kb + quad * 4;
#pragma unroll
        for (int r = 0; r < 4; ++r) {
          if (key0 + r > myq) v0[r] = -1e30f;
          if (key0 + 16 + r > myq) v1[r] = -1e30f;
        }
      }

      // softmax for row myq: in-reg over 8 vals + 2 shfl across quads
      float mloc = fmaxf(fmaxf(fmaxf(v0[0], v0[1]), fmaxf(v0[2], v0[3])),
                         fmaxf(fmaxf(v1[0], v1[1]), fmaxf(v1[2], v1[3])));
      mloc = fmaxf(mloc, __shfl_xor(mloc, 16, 64));
      mloc = fmaxf(mloc, __shfl_xor(mloc, 32, 64));
      const float mnew = fmaxf(m_i, mloc);
      float e0[4], e1[4];
      float sum = 0.f;
#pragma unroll
      for (int r = 0; r < 4; ++r) {
        e0[r] = __expf(v0[r] - mnew);
        e1[r] = __expf(v1[r] - mnew);
        sum += e0[r] + e1[r];
      }
      sum += __shfl_xor(sum, 16, 64);
      sum += __shfl_xor(sum, 32, 64);
      const float alpha = __expf(m_i - mnew);
      m_i = mnew;
      l_i = l_i * alpha + sum;

      // pack per-reg bf16 pair {tile0, tile1} and shuffle into A-layout
      u32 pk[4];
#pragma unroll
      for (int r = 0; r < 4; ++r) pk[r] = bf16bits(e0[r]) | (bf16bits(e1[r]) << 16);
      u32 a0[4], a1[4];
#pragma unroll
      for (int r = 0; r < 4; ++r) {
        a0[r] = (u32)__shfl((int)pk[r], src0, 64);
        a1[r] = (u32)__shfl((int)pk[r], src1, 64);
      }
      u32 w0, w1, w2, w3;
      if (hiTile) {
        w0 = (a0[0] >> 16) | (a0[1] & 0xffff0000u);
        w1 = (a0[2] >> 16) | (a0[3] & 0xffff0000u);
        w2 = (a1[0] >> 16) | (a1[1] & 0xffff0000u);
        w3 = (a1[2] >> 16) | (a1[3] & 0xffff0000u);
      } else {
        w0 = (a0[0] & 0xffffu) | (a0[1] << 16);
        w1 = (a0[2] & 0xffffu) | (a0[3] << 16);
        w2 = (a1[0] & 0xffffu) | (a1[1] << 16);
        w3 = (a1[2] & 0xffffu) | (a1[3] << 16);
      }
      bf16x8 pf = __builtin_bit_cast(bf16x8, (u32x4){w0, w1, w2, w3});

      // redistribute alpha to O rows (row = quad*4+r lives at src lane quad*4+r)
      float alpha_o[4];
#pragma unroll
      for (int r = 0; r < 4; ++r) alpha_o[r] = __shfl(alpha, quad * 4 + r, 64);

      // rescale O, then O += P V
#pragma unroll
      for (int n = 0; n < 8; ++n) {
#pragma unroll
        for (int r = 0; r < 4; ++r) o_acc[n][r] *= alpha_o[r];
      }
#pragma unroll
      for (int n = 0; n < 8; ++n) {
        bf16x8 vf = *(const bf16x8*)(Vs + (n * 16 + c) * SVS + quad * 8);
        o_acc[n] = __builtin_amdgcn_mfma_f32_16x16x32_bf16(pf, vf, o_acc[n], 0, 0, 0);
      }
    }
  }

  // epilogue: O /= l (l for row quad*4+r lives at lane quad*4+r), write out
  float l_o[4];
#pragma unroll
  for (int r = 0; r < 4; ++r) l_o[r] = __shfl(l_i, quad * 4 + r, 64);
#pragma unroll
  for (int n = 0; n < 8; ++n)
#pragma unroll
    for (int r = 0; r < 4; ++r) {
      const int row = q0 + w * 16 + quad * 4 + r;
      const float ov = o_acc[n][r] / l_o[r];
      attn_out[((size_t)b * S_ + row) * DM + h * HD + n * 16 + c] = (bf16)ov;
    }
}

// ---------------------------------------------------------------------------
extern "C" void kernel_launch(void* const* d_in, const int* in_sizes, int n_in,
                              void* d_out, int out_size, void* d_ws, size_t ws_size,
                              hipStream_t stream) {
  const float* hidden = (const float*)d_in[0];
  const float* cosT = (const float*)d_in[1];
  const float* sinT = (const float*)d_in[2];
  const float* Wqkv = (const float*)d_in[3];
  const float* Wout = (const float*)d_in[4];
  float* out = (float*)d_out;
  char* ws = (char*)d_ws;

  bf16* WqkvT = (bf16*)(ws + 0);
  bf16* q_r = (bf16*)(ws + 0);
  bf16* k_r = (bf16*)(ws + 33554432);
  bf16* WoutT = (bf16*)(ws + 50331648);
  bf16* h_bf = (bf16*)(ws + 83886080);
  bf16* attn_out = (bf16*)(ws + 83886080);
  bf16* v_t = (bf16*)(ws + 117440512);
  bf16* qkv = (bf16*)d_out;

  cast_f32_bf16<<<dim3(16384), dim3(256), 0, stream>>>(hidden, h_bf, B_ * S_ * DM);
  transpose_cast_w<<<dim3(QKV_DIM / 64, DM / 64), dim3(256), 0, stream>>>(Wqkv, WqkvT, DM, QKV_DIM);
  transpose_cast_w<<<dim3(DM / 64, DM / 64), dim3(256), 0, stream>>>(Wout, WoutT, DM, DM);
  gemm_bt<true><<<dim3(QKV_DIM / 128, (B_ * S_) / 128), dim3(256), 0, stream>>>(
      h_bf, WqkvT, (void*)qkv, B_ * S_, QKV_DIM, DM);
  rope_kernel<<<dim3(B_ * S_), dim3(128), 0, stream>>>(qkv, cosT, sinT, q_r, k_r);
  transpose_v<<<dim3(S_ / 64, HD / 64, B_ * NKV), dim3(256), 0, stream>>>(qkv, v_t);
  attn_kernel<<<dim3(B_ * NH, S_ / 64), dim3(256), 0, stream>>>(q_r, k_r, v_t, attn_out);
  gemm_bt<false><<<dim3(DM / 128, (B_ * S_) / 128), dim3(256), 0, stream>>>(
      attn_out, WoutT, (void*)out, B_ * S_, DM, DM);
}